// Round 2
// baseline (169.010 us; speedup 1.0000x reference)
//
#include <hip/hip_runtime.h>
#include <hip/hip_bf16.h>
#include <cstdint>
#include <cstddef>

#define L_SEQ 2048
#define BATCH 2
#define DM 1024
#define NH 16
#define DK 64
#define QKV_N 3072       // 3*DM
#define HEAD_STRIDE 192  // 3*DK
#define NX (4096 * 1024) // X element count
#define NW (3072 * 1024) // W element count

typedef short short8_t __attribute__((ext_vector_type(8)));
typedef short short4_t __attribute__((ext_vector_type(4)));
typedef float f32x4 __attribute__((ext_vector_type(4)));

#define MFMA32(a, b, c) __builtin_amdgcn_mfma_f32_16x16x32_bf16(a, b, c, 0, 0, 0)
#define MFMA16(a, b, c) __builtin_amdgcn_mfma_f32_16x16x16bf16_1k(a, b, c, 0, 0, 0)
// bare v_exp_f32 (2^x). exp2f() is an OCML libm call -- R10 regression.
#define EXP2(x) __builtin_amdgcn_exp2f(x)

// 2x fp32 -> packed bf16 pair (v_cvt_pk_bf16_f32 on gfx950), RNE.
static __device__ __forceinline__ unsigned pk2(float a, float b) {
  __hip_bfloat162 h = __float22bfloat162_rn(make_float2(a, b));
  union { __hip_bfloat162 h; unsigned u; } v;
  v.h = h;
  return v.u;
}

// async global->LDS, 16B per lane. LDS dest = wave-uniform base + lane*16.
static __device__ __forceinline__ void async_copy16(const unsigned short* g,
                                                    unsigned short* l) {
  __builtin_amdgcn_global_load_lds(
      (const __attribute__((address_space(1))) unsigned int*)g,
      (__attribute__((address_space(3))) unsigned int*)l, 16, 0, 0);
}

// ---------------------------------------------------------------------------
// fp32 -> bf16 cast of X and W into one contiguous bf16 buffer.
// ---------------------------------------------------------------------------
__global__ __launch_bounds__(256) void cast_kernel(
    const float* __restrict__ X, const float* __restrict__ W,
    unsigned short* __restrict__ dst) {
  const int e = (blockIdx.x * 256 + threadIdx.x) * 8;
  const float* src = (e < NX) ? &X[e] : &W[e - NX];
  const float4 v0 = *(const float4*)src;
  const float4 v1 = *(const float4*)(src + 4);
  union { short8_t s8; unsigned u[4]; } o;
  o.u[0] = pk2(v0.x, v0.y);
  o.u[1] = pk2(v0.z, v0.w);
  o.u[2] = pk2(v1.x, v1.y);
  o.u[3] = pk2(v1.z, v1.w);
  *(short8_t*)&dst[e] = o.s8;
}

// ---------------------------------------------------------------------------
// bf16 MFMA QKV GEMM, fused RoPE + q-scale epilogue, bf16 output.
// q-scale = 0.125 * log2(e): attention computes softmax in exp2-space.
// Epilogue uses __sincosf (HW v_sin/v_cos) and packed bf16 cvt.
// NOTE: no setprio here -- m190 measured T5 null/negative on lockstep GEMM.
// ---------------------------------------------------------------------------
__global__ __launch_bounds__(256) void qkv_gemm_bf16(
    const unsigned short* __restrict__ Xb, const unsigned short* __restrict__ Wb,
    unsigned short* __restrict__ qkvb) {
  __shared__ __align__(16) unsigned short As[2][128 * 32];  // [buf][m][k]
  __shared__ __align__(16) unsigned short Bs[2][128 * 32];  // [buf][n][k]
  const int t = threadIdx.x;
  const int w = t >> 6;
  const int lane = t & 63;
  const int L16 = lane & 15;
  const int quad = lane >> 4;
  const int m0 = blockIdx.y * 128;
  const int n0 = blockIdx.x * 128;
  const int wm = w & 1;
  const int wn = w >> 1;

  const int c0 = w * 128 + lane;
  const int c1 = c0 + 64;
  const unsigned short* gA0 = Xb + (size_t)(m0 + (c0 >> 2)) * 1024 + (c0 & 3) * 8;
  const unsigned short* gA1 = Xb + (size_t)(m0 + (c1 >> 2)) * 1024 + (c1 & 3) * 8;
  const unsigned short* gB0 = Wb + (size_t)(n0 + (c0 >> 2)) * 1024 + (c0 & 3) * 8;
  const unsigned short* gB1 = Wb + (size_t)(n0 + (c1 >> 2)) * 1024 + (c1 & 3) * 8;

  f32x4 acc[4][4];
#pragma unroll
  for (int i = 0; i < 4; ++i)
#pragma unroll
    for (int j = 0; j < 4; ++j) acc[i][j] = (f32x4){0.f, 0.f, 0.f, 0.f};

  // prologue: stage tile 0 into buf 0
  async_copy16(gA0, &As[0][w * 1024]);
  async_copy16(gA1, &As[0][w * 1024 + 512]);
  async_copy16(gB0, &Bs[0][w * 1024]);
  async_copy16(gB1, &Bs[0][w * 1024 + 512]);

#define GBODY(K0, BUF)                                                        \
  {                                                                           \
    __syncthreads(); /* drains DMA(K0); prior readers of buf done */          \
    if ((K0) + 32 < 1024) {                                                   \
      async_copy16(gA0 + (K0) + 32, &As[(BUF) ^ 1][w * 1024]);                \
      async_copy16(gA1 + (K0) + 32, &As[(BUF) ^ 1][w * 1024 + 512]);          \
      async_copy16(gB0 + (K0) + 32, &Bs[(BUF) ^ 1][w * 1024]);                \
      async_copy16(gB1 + (K0) + 32, &Bs[(BUF) ^ 1][w * 1024 + 512]);          \
    }                                                                         \
    short8_t af[4], bfr[4];                                                   \
    _Pragma("unroll") for (int mt = 0; mt < 4; ++mt)                          \
        af[mt] = *(const short8_t*)                                           \
            &As[BUF][(wm * 64 + mt * 16 + L16) * 32 + quad * 8];              \
    _Pragma("unroll") for (int nt = 0; nt < 4; ++nt)                          \
        bfr[nt] = *(const short8_t*)                                          \
            &Bs[BUF][(wn * 64 + nt * 16 + L16) * 32 + quad * 8];              \
    _Pragma("unroll") for (int mt = 0; mt < 4; ++mt)                          \
        _Pragma("unroll") for (int nt = 0; nt < 4; ++nt)                      \
            acc[mt][nt] = MFMA32(af[mt], bfr[nt], acc[mt][nt]);               \
  }

  for (int k0 = 0; k0 < 1024; k0 += 64) {
    GBODY(k0, 0)
    GBODY(k0 + 32, 1)
  }

  const int nbase = n0 + wn * 64 + L16;
  const int chunk = (n0 >> 6) + wn;
  const int type = chunk % 3;        // 0=q, 1=k, 2=v
  if (type == 2) {
#pragma unroll
    for (int mt = 0; mt < 4; ++mt) {
      const int mbase = m0 + wm * 64 + mt * 16 + quad * 4;
#pragma unroll
      for (int reg = 0; reg < 4; ++reg) {
        const size_t r = (size_t)(mbase + reg) * QKV_N + nbase;
        const unsigned u0 = pk2(acc[mt][0][reg], acc[mt][1][reg]);
        const unsigned u1 = pk2(acc[mt][2][reg], acc[mt][3][reg]);
        qkvb[r]      = (unsigned short)u0;
        qkvb[r + 16] = (unsigned short)(u0 >> 16);
        qkvb[r + 32] = (unsigned short)u1;
        qkvb[r + 48] = (unsigned short)(u1 >> 16);
      }
    }
  } else {
    // q gets 0.125*log2(e) so attention can use bare v_exp (exp2-space).
    const float qs = (type == 0) ? 0.18033688011112042f : 1.0f;
    const float theta = exp2f(-(float)L16 * 0.8304820237218405f);
#pragma unroll
    for (int mt = 0; mt < 4; ++mt) {
      const int mbase = m0 + wm * 64 + mt * 16 + quad * 4;  // even
      const int lb = mbase >> 1;
      float sv[2], cv[2];
      __sincosf((float)lb * theta, &sv[0], &cv[0]);
      __sincosf((float)(lb + 1) * theta, &sv[1], &cv[1]);
#pragma unroll
      for (int reg = 0; reg < 4; ++reg) {
        const int li = reg >> 1;
        const float v0 = acc[mt][0][reg], v1 = acc[mt][1][reg];
        const float r0 = v0 * cv[li] - v1 * sv[li];
        const float r1 = v1 * cv[li] + v0 * sv[li];
        const size_t r = (size_t)(mbase + reg) * QKV_N + nbase;
        const unsigned u0 = pk2(r0 * qs, r1 * qs);
        const unsigned u1 = pk2(acc[mt][2][reg] * qs, acc[mt][3][reg] * qs);
        qkvb[r]      = (unsigned short)u0;
        qkvb[r + 16] = (unsigned short)(u0 >> 16);
        qkvb[r + 32] = (unsigned short)u1;
        qkvb[r + 48] = (unsigned short)(u1 >> 16);
      }
    }
  }
}

// ---------------------------------------------------------------------------
// bf16 MFMA attention, register-resident P, exp2-space softmax.
// 2 m-tiles per wave (block = 128 q-rows, grid 512). kt-loop unrolled x2.
// XOR-swizzled Ks + column-group-swizzled Vt (R7-verified).
// p = 2^s via __builtin_amdgcn_exp2f (bare v_exp_f32 -- NOT exp2f/libm).
// R1: T5 s_setprio(1) around both MFMA clusters (measured +4-7% on attn,
// m191-class structure: independent blocks, waves at different kt phases).
// ---------------------------------------------------------------------------
__global__ __launch_bounds__(256) void attn_mfma_kernel(
    const unsigned short* __restrict__ qkvb, float* __restrict__ out) {
  __shared__ __align__(16) unsigned short Ks[2][4096];    // [buf][r*64 + swz]
  __shared__ __align__(16) unsigned short Vt[2][64][72];  // [buf][d][j] swizzled

  const int t = threadIdx.x;
  const int w = t >> 6;
  const int lane = t & 63;
  const int L16 = lane & 15;
  const int quad = lane >> 4;
  const int l0 = blockIdx.x * 128;
  const int b = blockIdx.y & 1;
  const int h = blockIdx.y >> 1;
  const int hoff = h * HEAD_STRIDE;

  const f32x4 z4 = {0.f, 0.f, 0.f, 0.f};

  // ---- hoisted Q B-fragments for 2 m-tiles ----
  short8_t bq[2][2];
#pragma unroll
  for (int mt = 0; mt < 2; ++mt)
#pragma unroll
    for (int kc = 0; kc < 2; ++kc)
      bq[mt][kc] = *(const short8_t*)
          &qkvb[((size_t)((l0 + w * 32 + mt * 16 + L16) * 2 + b)) * QKV_N +
                hoff + kc * 32 + quad * 8];

  f32x4 oc[2][4];
  float l_part[2] = {0.f, 0.f};
#pragma unroll
  for (int mt = 0; mt < 2; ++mt)
#pragma unroll
    for (int dt = 0; dt < 4; ++dt) oc[mt][dt] = z4;

  // ---- K async-copy state (XOR-swizzled source column) ----
  const int kr0 = w * 8 + (lane >> 3);
  const int kcs = ((lane & 7) ^ (lane >> 3)) * 8;
  const unsigned short* gK0 =
      qkvb + (size_t)(kr0 * 2 + b) * QKV_N + hoff + 64 + kcs;
  const unsigned short* gK1 = gK0 + (size_t)64 * QKV_N;
  const size_t kstep = (size_t)128 * QKV_N;

  // ---- V prefetch state ----
  const int vr4 = (t >> 4) * 4;
  const int vc4 = (t & 15) * 4;
  const int cgbase = vr4 >> 3;
  const int joff = vr4 & 7;
  short4_t rv[4];

#define LOAD_V(KT)                                                            \
  {                                                                           \
    const int j0 = (KT) * 64;                                                 \
    _Pragma("unroll") for (int r = 0; r < 4; ++r)                             \
        rv[r] = *(const short4_t*)&qkvb[((size_t)((j0 + vr4 + r) * 2 + b)) *  \
                                        QKV_N + hoff + 128 + vc4];            \
  }

  LOAD_V(0)
  async_copy16(gK0, &Ks[0][w * 512]);
  async_copy16(gK1, &Ks[0][w * 512 + 2048]);

  const int rsw = (L16 & 7);

#define ABODY(KT, BUF)                                                        \
  {                                                                           \
    { /* V micro-transpose -> Vt[BUF] */                                      \
      short4_t s0 = {rv[0][0], rv[1][0], rv[2][0], rv[3][0]};                 \
      short4_t s1 = {rv[0][1], rv[1][1], rv[2][1], rv[3][1]};                 \
      short4_t s2 = {rv[0][2], rv[1][2], rv[2][2], rv[3][2]};                 \
      short4_t s3 = {rv[0][3], rv[1][3], rv[2][3], rv[3][3]};                 \
      const int cg0 = (cgbase + ((vc4 >> 2) & 7)) & 7;                        \
      *(short4_t*)&Vt[BUF][vc4 + 0][cg0 * 8 + joff] = s0;                     \
      *(short4_t*)&Vt[BUF][vc4 + 1][cg0 * 8 + joff] = s1;                     \
      *(short4_t*)&Vt[BUF][vc4 + 2][cg0 * 8 + joff] = s2;                     \
      *(short4_t*)&Vt[BUF][vc4 + 3][cg0 * 8 + joff] = s3;                     \
    }                                                                         \
    __syncthreads();                                                          \
    if ((KT) + 1 < 32) {                                                      \
      async_copy16(gK0 + (size_t)((KT) + 1) * kstep, &Ks[(BUF) ^ 1][w * 512]);\
      async_copy16(gK1 + (size_t)((KT) + 1) * kstep,                          \
                   &Ks[(BUF) ^ 1][w * 512 + 2048]);                           \
      LOAD_V((KT) + 1)                                                        \
    }                                                                         \
    f32x4 sc0[4], sc1[4];                                                     \
    __builtin_amdgcn_s_setprio(1);                                            \
    _Pragma("unroll") for (int nt = 0; nt < 4; ++nt) {                        \
      const short8_t ak0 = *(const short8_t*)                                 \
          &Ks[BUF][(nt * 16 + L16) * 64 + (quad ^ rsw) * 8];                  \
      const short8_t ak1 = *(const short8_t*)                                 \
          &Ks[BUF][(nt * 16 + L16) * 64 + ((quad + 4) ^ rsw) * 8];            \
      f32x4 t0 = MFMA32(ak0, bq[0][0], z4);                                   \
      sc0[nt] = MFMA32(ak1, bq[0][1], t0);                                    \
      f32x4 t1 = MFMA32(ak0, bq[1][0], z4);                                   \
      sc1[nt] = MFMA32(ak1, bq[1][1], t1);                                    \
    }                                                                         \
    __builtin_amdgcn_s_setprio(0);                                            \
    short4_t pf[2][4];                                                        \
    _Pragma("unroll") for (int nt = 0; nt < 4; ++nt) {                        \
      float p0 = EXP2(sc0[nt][0]), p1 = EXP2(sc0[nt][1]);                     \
      float p2 = EXP2(sc0[nt][2]), p3 = EXP2(sc0[nt][3]);                     \
      l_part[0] += (p0 + p1) + (p2 + p3);                                     \
      union { short4_t s4; unsigned u[2]; } pu0;                              \
      pu0.u[0] = pk2(p0, p1);                                                 \
      pu0.u[1] = pk2(p2, p3);                                                 \
      pf[0][nt] = pu0.s4;                                                     \
      float q0 = EXP2(sc1[nt][0]), q1 = EXP2(sc1[nt][1]);                     \
      float q2 = EXP2(sc1[nt][2]), q3 = EXP2(sc1[nt][3]);                     \
      l_part[1] += (q0 + q1) + (q2 + q3);                                     \
      union { short4_t s4; unsigned u[2]; } pu1;                              \
      pu1.u[0] = pk2(q0, q1);                                                 \
      pu1.u[1] = pk2(q2, q3);                                                 \
      pf[1][nt] = pu1.s4;                                                     \
    }                                                                         \
    __builtin_amdgcn_s_setprio(1);                                            \
    _Pragma("unroll") for (int nt = 0; nt < 4; ++nt) {                        \
      _Pragma("unroll") for (int dt = 0; dt < 4; ++dt) {                      \
        const int d = dt * 16 + L16;                                          \
        const int g = 2 * nt + (quad >> 1);                                   \
        const int cg = (g + ((d >> 2) & 7)) & 7;                              \
        const short4_t vf =                                                   \
            *(const short4_t*)&Vt[BUF][d][cg * 8 + (quad & 1) * 4];           \
        oc[0][dt] = MFMA16(vf, pf[0][nt], oc[0][dt]);                         \
        oc[1][dt] = MFMA16(vf, pf[1][nt], oc[1][dt]);                         \
      }                                                                       \
    }                                                                         \
    __builtin_amdgcn_s_setprio(0);                                            \
  }

  for (int kt = 0; kt < 32; kt += 2) {
    ABODY(kt, 0)
    ABODY(kt + 1, 1)
  }

  // ---- final row-sum reductions + epilogue ----
#pragma unroll
  for (int mt = 0; mt < 2; ++mt) {
    float l = l_part[mt];
    l += __shfl_xor(l, 16);
    l += __shfl_xor(l, 32);
    const float inv = 1.f / l;
    const int qrow = l0 + w * 32 + mt * 16 + L16;
    const size_t rbase = ((size_t)(qrow * 2 + b)) * DM + h * DK;
#pragma unroll
    for (int dt = 0; dt < 4; ++dt) {
      *(float4*)&out[rbase + dt * 16 + quad * 4] =
          make_float4(oc[mt][dt][0] * inv, oc[mt][dt][1] * inv,
                      oc[mt][dt][2] * inv, oc[mt][dt][3] * inv);
    }
  }
}

// ---------------------------------------------------------------------------
extern "C" void kernel_launch(void* const* d_in, const int* in_sizes, int n_in,
                              void* d_out, int out_size, void* d_ws,
                              size_t ws_size, hipStream_t stream) {
  const float* x = (const float*)d_in[0];
  const float* w = (const float*)d_in[1];
  float* out = (float*)d_out;
  unsigned short* bf = (unsigned short*)d_ws;          // Xb (8MB) + Wb (6MB)
  unsigned short* Xb = bf;
  unsigned short* Wb = bf + NX;
  unsigned short* qkvb =
      (unsigned short*)((char*)d_ws + (16u << 20));    // 24 MB bf16 qkv

  cast_kernel<<<(NX + NW) / (256 * 8), 256, 0, stream>>>(x, w, bf);
  qkv_gemm_bf16<<<dim3(QKV_N / 128, (L_SEQ * BATCH) / 128), 256, 0, stream>>>(
      Xb, Wb, qkvb);
  attn_mfma_kernel<<<dim3(L_SEQ / 128, NH * BATCH), 256, 0, stream>>>(qkvb, out);
}